// Round 4
// baseline (980.808 us; speedup 1.0000x reference)
//
#include <hip/hip_runtime.h>
#include <stdint.h>

#define H_DIM 4096
#define I_DIM 11008
#define T_DIM 4096

typedef int i32x4 __attribute__((ext_vector_type(4)));
typedef const void __attribute__((address_space(1))) gvoid_t;
typedef void __attribute__((address_space(3))) svoid_t;

__device__ __forceinline__ void gload_lds16(const void* gsrc, void* ldst) {
    __builtin_amdgcn_global_load_lds((gvoid_t*)gsrc, (svoid_t*)ldst, 16, 0, 0);
}
__device__ __forceinline__ void wait_vmcnt0() {
    asm volatile("s_waitcnt vmcnt(0)" ::: "memory");
}
__device__ __forceinline__ void wait_lgkm0() {
    asm volatile("s_waitcnt lgkmcnt(0)" ::: "memory");
    __builtin_amdgcn_sched_barrier(0);
}
__device__ __forceinline__ void barrier_() {
    asm volatile("s_barrier" ::: "memory");
}

__device__ __forceinline__ uint32_t pack4(int4 v) {
    uint32_t r = (uint32_t)(uint8_t)v.x;
    r |= (uint32_t)(uint8_t)v.y << 8;
    r |= (uint32_t)(uint8_t)v.z << 16;
    r |= (uint32_t)(uint8_t)v.w << 24;
    return r;
}

// int32 -> int8 pack (truncate low byte; values already int8-range)
__global__ void convert_kernel(const int* __restrict__ src, int8_t* __restrict__ dst,
                               int n4) {
    int idx = blockIdx.x * blockDim.x + threadIdx.x;
    int stride = gridDim.x * blockDim.x;
    for (int i = idx; i < n4; i += stride) {
        int4 v = ((const int4*)src)[i];
        ((uint32_t*)dst)[i] = pack4(v);
    }
}

#define MFMA_I8 __builtin_amdgcn_mfma_i32_16x16x64_i8

// ---------------------------------------------------------------------------
// gateup: BM=256 BN=128 BK=128B, 8 waves (2Mx4N), per-wave 128x32 with two
// accumulator sets (G,U). m201-style per-phase books: 4 phases/K-tile, each
// {stage? ; ds_read ; barrier ; lgkm0 ; setprio ; 16 MFMA ; setprio ; barrier},
// all prefetch front-loaded in phases 0-1, single vmcnt(0) at tile end.
// ---------------------------------------------------------------------------
__global__ __launch_bounds__(512, 2)
void gateup_kernel(const int8_t* __restrict__ x8, const int8_t* __restrict__ gw8,
                   const int8_t* __restrict__ uw8,
                   const float* __restrict__ galpha, const float* __restrict__ gbias,
                   const float* __restrict__ ualpha, const float* __restrict__ ubias,
                   const float* __restrict__ scale_p, int8_t* __restrict__ hq)
{
    __shared__ __align__(16) int8_t lsA[2][2][256 * 64];  // [buf][kk][row*64+slot]
    __shared__ __align__(16) int8_t lsG[2][2][128 * 64];
    __shared__ __align__(16) int8_t lsU[2][2][128 * 64];

    const int nwg = gridDim.x;                 // 1376, %8==0
    int bid = blockIdx.x;
    bid = (bid & 7) * (nwg >> 3) + (bid >> 3); // bijective XCD swizzle
    const int mt = bid & 15;
    const int nt = bid >> 4;
    const int m0 = mt << 8;
    const int n0 = nt << 7;

    const int tid  = threadIdx.x;
    const int lane = tid & 63;
    const int wid  = tid >> 6;
    const int wr   = wid >> 2;                 // 0..1
    const int wc   = wid & 3;                  // 0..3
    const int lr   = lane & 15;
    const int rdsw = ((lane >> 4) ^ ((lr >> 1) & 3)) << 4;

    const int srow = tid >> 2;
    const int scol = ((tid & 3) ^ ((tid >> 3) & 3)) << 4;
    const int woff = wid << 10;

    const int8_t* As = x8  + (size_t)(m0 + srow) * H_DIM + scol;
    const int8_t* Gs = gw8 + (size_t)(n0 + srow) * H_DIM + scol;
    const int8_t* Us = uw8 + (size_t)(n0 + srow) * H_DIM + scol;

    i32x4 accg[8][2], accu[8][2];
#pragma unroll
    for (int mf = 0; mf < 8; ++mf)
#pragma unroll
        for (int nf = 0; nf < 2; ++nf) {
            accg[mf][nf] = i32x4{0, 0, 0, 0};
            accu[mf][nf] = i32x4{0, 0, 0, 0};
        }

    const int aro = (wr * 128 + lr) * 64 + rdsw;   // + mf*1024
    const int gro = (wc * 32 + lr) * 64 + rdsw;    // + nf*1024

#define STA(buf, kk, rh, kb) gload_lds16(As + (size_t)(rh) * 128 * H_DIM + (kb) + (kk) * 64, \
                                         &lsA[buf][kk][(rh) * 8192 + woff])
#define STG(buf, kk, kb)     gload_lds16(Gs + (kb) + (kk) * 64, &lsG[buf][kk][woff])
#define STU(buf, kk, kb)     gload_lds16(Us + (kb) + (kk) * 64, &lsU[buf][kk][woff])

    // prologue: tile 0 fully staged
    STA(0, 0, 0, 0); STA(0, 0, 1, 0); STA(0, 1, 0, 0); STA(0, 1, 1, 0);
    STG(0, 0, 0); STG(0, 1, 0); STU(0, 0, 0); STU(0, 1, 0);
    wait_vmcnt0();
    barrier_();

    const int NKT = H_DIM / 128;  // 32
    for (int t = 0; t < NKT; ++t) {
        const int cur = t & 1, nxt = cur ^ 1;
        const int kbn = ((t + 1 < NKT) ? (t + 1) : 0) << 7;
        i32x4 af[8], gf[4], uf[4];
        // ---- phase 0: stage A(t+1); read A-mh0 + G; MFMA G x mh0 ----
        STA(nxt, 0, 0, kbn); STA(nxt, 0, 1, kbn); STA(nxt, 1, 0, kbn); STA(nxt, 1, 1, kbn);
#pragma unroll
        for (int kk = 0; kk < 2; ++kk) {
#pragma unroll
            for (int mf = 0; mf < 4; ++mf)
                af[kk * 4 + mf] = *(const i32x4*)&lsA[cur][kk][aro + mf * 1024];
#pragma unroll
            for (int nf = 0; nf < 2; ++nf)
                gf[kk * 2 + nf] = *(const i32x4*)&lsG[cur][kk][gro + nf * 1024];
        }
        barrier_();
        wait_lgkm0();
        __builtin_amdgcn_s_setprio(1);
#pragma unroll
        for (int kk = 0; kk < 2; ++kk)
#pragma unroll
            for (int mf = 0; mf < 4; ++mf)
#pragma unroll
                for (int nf = 0; nf < 2; ++nf)
                    accg[mf][nf] = MFMA_I8(af[kk * 4 + mf], gf[kk * 2 + nf], accg[mf][nf], 0, 0, 0);
        __builtin_amdgcn_s_setprio(0);
        barrier_();
        // ---- phase 1: stage G,U(t+1); read U; MFMA U x mh0 ----
        STG(nxt, 0, kbn); STG(nxt, 1, kbn); STU(nxt, 0, kbn); STU(nxt, 1, kbn);
#pragma unroll
        for (int kk = 0; kk < 2; ++kk)
#pragma unroll
            for (int nf = 0; nf < 2; ++nf)
                uf[kk * 2 + nf] = *(const i32x4*)&lsU[cur][kk][gro + nf * 1024];
        barrier_();
        wait_lgkm0();
        __builtin_amdgcn_s_setprio(1);
#pragma unroll
        for (int kk = 0; kk < 2; ++kk)
#pragma unroll
            for (int mf = 0; mf < 4; ++mf)
#pragma unroll
                for (int nf = 0; nf < 2; ++nf)
                    accu[mf][nf] = MFMA_I8(af[kk * 4 + mf], uf[kk * 2 + nf], accu[mf][nf], 0, 0, 0);
        __builtin_amdgcn_s_setprio(0);
        barrier_();
        // ---- phase 2: read A-mh1; MFMA G x mh1 (reuse gf) ----
#pragma unroll
        for (int kk = 0; kk < 2; ++kk)
#pragma unroll
            for (int mf = 0; mf < 4; ++mf)
                af[kk * 4 + mf] = *(const i32x4*)&lsA[cur][kk][aro + (mf + 4) * 1024];
        barrier_();
        wait_lgkm0();
        __builtin_amdgcn_s_setprio(1);
#pragma unroll
        for (int kk = 0; kk < 2; ++kk)
#pragma unroll
            for (int mf = 0; mf < 4; ++mf)
#pragma unroll
                for (int nf = 0; nf < 2; ++nf)
                    accg[mf + 4][nf] = MFMA_I8(af[kk * 4 + mf], gf[kk * 2 + nf], accg[mf + 4][nf], 0, 0, 0);
        __builtin_amdgcn_s_setprio(0);
        barrier_();
        // ---- phase 3: MFMA U x mh1 (reuse af, uf); tile-end drain ----
        __builtin_amdgcn_s_setprio(1);
#pragma unroll
        for (int kk = 0; kk < 2; ++kk)
#pragma unroll
            for (int mf = 0; mf < 4; ++mf)
#pragma unroll
                for (int nf = 0; nf < 2; ++nf)
                    accu[mf + 4][nf] = MFMA_I8(af[kk * 4 + mf], uf[kk * 2 + nf], accu[mf + 4][nf], 0, 0, 0);
        __builtin_amdgcn_s_setprio(0);
        wait_vmcnt0();
        barrier_();
    }
#undef STA
#undef STG
#undef STU

    // epilogue: dequant, SwiGLU, requant
    const float scale = *scale_p;
#pragma unroll
    for (int nf = 0; nf < 2; ++nf) {
        const int col = n0 + wc * 32 + nf * 16 + lr;
        const float gA = galpha[col], gB = gbias[col];
        const float uA = ualpha[col], uB = ubias[col];
#pragma unroll
        for (int mf = 0; mf < 8; ++mf) {
            const int row0 = m0 + wr * 128 + mf * 16 + (lane >> 4) * 4;
#pragma unroll
            for (int j = 0; j < 4; ++j) {
                float g = (float)accg[mf][nf][j] * gA + gB;
                float u = (float)accu[mf][nf][j] * uA + uB;
                float s = 1.0f / (1.0f + __expf(-g));
                float h = g * s * u;
                float q = rintf(h / scale);
                q = fminf(127.0f, fmaxf(-128.0f, q));
                hq[(size_t)(row0 + j) * I_DIM + col] = (int8_t)q;
            }
        }
    }
}

// ---------------------------------------------------------------------------
// down: BM=256 BN=256 BK=128B, 8 waves (2Mx4N), per-wave 128x64. Same books.
// ---------------------------------------------------------------------------
__global__ __launch_bounds__(512, 2)
void down_kernel(const int8_t* __restrict__ hq, const int8_t* __restrict__ dw8,
                 const float* __restrict__ dalpha, const float* __restrict__ dbias,
                 float* __restrict__ out)
{
    __shared__ __align__(16) int8_t lsA[2][2][256 * 64];
    __shared__ __align__(16) int8_t lsB[2][2][256 * 64];

    const int nwg = gridDim.x;                 // 256
    int bid = blockIdx.x;
    bid = (bid & 7) * (nwg >> 3) + (bid >> 3);
    const int mt = bid & 15;
    const int nt = bid >> 4;
    const int m0 = mt << 8;
    const int n0 = nt << 8;

    const int tid  = threadIdx.x;
    const int lane = tid & 63;
    const int wid  = tid >> 6;
    const int wr   = wid >> 2;
    const int wc   = wid & 3;
    const int lr   = lane & 15;
    const int rdsw = ((lane >> 4) ^ ((lr >> 1) & 3)) << 4;

    const int srow = tid >> 2;
    const int scol = ((tid & 3) ^ ((tid >> 3) & 3)) << 4;
    const int woff = wid << 10;

    const int8_t* Ap = hq  + (size_t)(m0 + srow) * I_DIM + scol;
    const int8_t* Bp = dw8 + (size_t)(n0 + srow) * I_DIM + scol;

    i32x4 acc[8][4];
#pragma unroll
    for (int mf = 0; mf < 8; ++mf)
#pragma unroll
        for (int nf = 0; nf < 4; ++nf) acc[mf][nf] = i32x4{0, 0, 0, 0};

    const int aro = (wr * 128 + lr) * 64 + rdsw;   // + mf*1024
    const int bro = (wc * 64 + lr) * 64 + rdsw;    // + nf*1024

#define SDA(buf, kk, rh, kb) gload_lds16(Ap + (size_t)(rh) * 128 * I_DIM + (kb) + (kk) * 64, \
                                         &lsA[buf][kk][(rh) * 8192 + woff])
#define SDB(buf, kk, rh, kb) gload_lds16(Bp + (size_t)(rh) * 128 * I_DIM + (kb) + (kk) * 64, \
                                         &lsB[buf][kk][(rh) * 8192 + woff])

    SDA(0, 0, 0, 0); SDA(0, 0, 1, 0); SDA(0, 1, 0, 0); SDA(0, 1, 1, 0);
    SDB(0, 0, 0, 0); SDB(0, 0, 1, 0); SDB(0, 1, 0, 0); SDB(0, 1, 1, 0);
    wait_vmcnt0();
    barrier_();

    const int NKT = I_DIM / 128;  // 86
    for (int t = 0; t < NKT; ++t) {
        const int cur = t & 1, nxt = cur ^ 1;
        const int kbn = ((t + 1 < NKT) ? (t + 1) : 0) << 7;
        i32x4 af[8], b0[4], b1[4];
        // ---- phase 0: stage A(t+1); read A-mh0 + B-nh0; MFMA ----
        SDA(nxt, 0, 0, kbn); SDA(nxt, 0, 1, kbn); SDA(nxt, 1, 0, kbn); SDA(nxt, 1, 1, kbn);
#pragma unroll
        for (int kk = 0; kk < 2; ++kk) {
#pragma unroll
            for (int mf = 0; mf < 4; ++mf)
                af[kk * 4 + mf] = *(const i32x4*)&lsA[cur][kk][aro + mf * 1024];
#pragma unroll
            for (int nf = 0; nf < 2; ++nf)
                b0[kk * 2 + nf] = *(const i32x4*)&lsB[cur][kk][bro + nf * 1024];
        }
        barrier_();
        wait_lgkm0();
        __builtin_amdgcn_s_setprio(1);
#pragma unroll
        for (int kk = 0; kk < 2; ++kk)
#pragma unroll
            for (int mf = 0; mf < 4; ++mf)
#pragma unroll
                for (int nf = 0; nf < 2; ++nf)
                    acc[mf][nf] = MFMA_I8(af[kk * 4 + mf], b0[kk * 2 + nf], acc[mf][nf], 0, 0, 0);
        __builtin_amdgcn_s_setprio(0);
        barrier_();
        // ---- phase 1: stage B(t+1); read B-nh1; MFMA mh0 x nh1 ----
        SDB(nxt, 0, 0, kbn); SDB(nxt, 0, 1, kbn); SDB(nxt, 1, 0, kbn); SDB(nxt, 1, 1, kbn);
#pragma unroll
        for (int kk = 0; kk < 2; ++kk)
#pragma unroll
            for (int nf = 0; nf < 2; ++nf)
                b1[kk * 2 + nf] = *(const i32x4*)&lsB[cur][kk][bro + (nf + 2) * 1024];
        barrier_();
        wait_lgkm0();
        __builtin_amdgcn_s_setprio(1);
#pragma unroll
        for (int kk = 0; kk < 2; ++kk)
#pragma unroll
            for (int mf = 0; mf < 4; ++mf)
#pragma unroll
                for (int nf = 0; nf < 2; ++nf)
                    acc[mf][nf + 2] = MFMA_I8(af[kk * 4 + mf], b1[kk * 2 + nf], acc[mf][nf + 2], 0, 0, 0);
        __builtin_amdgcn_s_setprio(0);
        barrier_();
        // ---- phase 2: read A-mh1; MFMA mh1 x nh0 (reuse b0) ----
#pragma unroll
        for (int kk = 0; kk < 2; ++kk)
#pragma unroll
            for (int mf = 0; mf < 4; ++mf)
                af[kk * 4 + mf] = *(const i32x4*)&lsA[cur][kk][aro + (mf + 4) * 1024];
        barrier_();
        wait_lgkm0();
        __builtin_amdgcn_s_setprio(1);
#pragma unroll
        for (int kk = 0; kk < 2; ++kk)
#pragma unroll
            for (int mf = 0; mf < 4; ++mf)
#pragma unroll
                for (int nf = 0; nf < 2; ++nf)
                    acc[mf + 4][nf] = MFMA_I8(af[kk * 4 + mf], b0[kk * 2 + nf], acc[mf + 4][nf], 0, 0, 0);
        __builtin_amdgcn_s_setprio(0);
        barrier_();
        // ---- phase 3: MFMA mh1 x nh1 (reuse af, b1); tile-end drain ----
        __builtin_amdgcn_s_setprio(1);
#pragma unroll
        for (int kk = 0; kk < 2; ++kk)
#pragma unroll
            for (int mf = 0; mf < 4; ++mf)
#pragma unroll
                for (int nf = 0; nf < 2; ++nf)
                    acc[mf + 4][nf + 2] = MFMA_I8(af[kk * 4 + mf], b1[kk * 2 + nf], acc[mf + 4][nf + 2], 0, 0, 0);
        __builtin_amdgcn_s_setprio(0);
        wait_vmcnt0();
        barrier_();
    }
#undef SDA
#undef SDB

#pragma unroll
    for (int nf = 0; nf < 4; ++nf) {
        const int col = n0 + wc * 64 + nf * 16 + lr;
        const float dA = dalpha[col], dB = dbias[col];
#pragma unroll
        for (int mf = 0; mf < 8; ++mf) {
            const int row0 = m0 + wr * 128 + mf * 16 + (lane >> 4) * 4;
#pragma unroll
            for (int j = 0; j < 4; ++j) {
                out[(size_t)(row0 + j) * H_DIM + col] = (float)acc[mf][nf][j] * dA + dB;
            }
        }
    }
}

extern "C" void kernel_launch(void* const* d_in, const int* in_sizes, int n_in,
                              void* d_out, int out_size, void* d_ws, size_t ws_size,
                              hipStream_t stream) {
    const int* x32  = (const int*)d_in[0];
    const int* gw32 = (const int*)d_in[1];
    const int* uw32 = (const int*)d_in[2];
    const int* dw32 = (const int*)d_in[3];
    const float* ga = (const float*)d_in[4];
    const float* gb = (const float*)d_in[5];
    const float* ua = (const float*)d_in[6];
    const float* ub = (const float*)d_in[7];
    const float* da = (const float*)d_in[8];
    const float* db = (const float*)d_in[9];
    const float* sc = (const float*)d_in[10];
    float* out = (float*)d_out;

    const size_t SZ_X8 = (size_t)T_DIM * H_DIM;
    const size_t SZ_W  = (size_t)I_DIM * H_DIM;
    const size_t SZ_HQ = (size_t)T_DIM * I_DIM;

    int8_t* gw8 = (int8_t*)d_ws;              // reused for dw8 later
    int8_t* uw8 = gw8 + SZ_W;
    int8_t* hq  = uw8 + SZ_W;
    int8_t* x8  = hq + SZ_HQ;

    convert_kernel<<<dim3(2048), dim3(256), 0, stream>>>(x32, x8, (int)(SZ_X8 / 4));
    convert_kernel<<<dim3(2048), dim3(256), 0, stream>>>(gw32, gw8, (int)(SZ_W / 4));
    convert_kernel<<<dim3(2048), dim3(256), 0, stream>>>(uw32, uw8, (int)(SZ_W / 4));
    gateup_kernel<<<dim3(16 * 86), dim3(512), 0, stream>>>(
        x8, gw8, uw8, ga, gb, ua, ub, sc, hq);
    int8_t* dw8 = gw8;   // overwrite gate weights (stream-ordered after gateup)
    convert_kernel<<<dim3(2048), dim3(256), 0, stream>>>(dw32, dw8, (int)(SZ_W / 4));
    down_kernel<<<dim3(16 * 16), dim3(512), 0, stream>>>(hq, dw8, da, db, out);
}

// Round 5
// 823.024 us; speedup vs baseline: 1.1917x; 1.1917x over previous
//
#include <hip/hip_runtime.h>
#include <stdint.h>

#define H_DIM 4096
#define I_DIM 11008
#define T_DIM 4096

typedef int i32x4 __attribute__((ext_vector_type(4)));
typedef const void __attribute__((address_space(1))) gvoid_t;
typedef void __attribute__((address_space(3))) svoid_t;

__device__ __forceinline__ void gload_lds16(const void* gsrc, void* ldst) {
    __builtin_amdgcn_global_load_lds((gvoid_t*)gsrc, (svoid_t*)ldst, 16, 0, 0);
}

__device__ __forceinline__ uint32_t pack4(int4 v) {
    uint32_t r = (uint32_t)(uint8_t)v.x;
    r |= (uint32_t)(uint8_t)v.y << 8;
    r |= (uint32_t)(uint8_t)v.z << 16;
    r |= (uint32_t)(uint8_t)v.w << 24;
    return r;
}

// int32 -> int8 pack (truncate low byte; values already int8-range)
__global__ void convert_kernel(const int* __restrict__ src, int8_t* __restrict__ dst,
                               int n4) {
    int idx = blockIdx.x * blockDim.x + threadIdx.x;
    int stride = gridDim.x * blockDim.x;
    for (int i = idx; i < n4; i += stride) {
        int4 v = ((const int4*)src)[i];
        ((uint32_t*)dst)[i] = pack4(v);
    }
}

#define MFMA_I8 __builtin_amdgcn_mfma_i32_16x16x64_i8

// ---------------------------------------------------------------------------
// gateup: BM=128 BN=128 BK=64B, 4 waves (1M x 4N), wave = 128x32 output with
// dual accumulators (G,U). R2-style simple schedule (stage; sync; compute;
// sync) -- 2 blocks/CU overlap LDS and MFMA pipes naturally. XOR-swizzled LDS
// (verified 0-conflict), XCD-swizzled blockIdx.
// ---------------------------------------------------------------------------
__global__ __launch_bounds__(256, 2)
void gateup_kernel(const int8_t* __restrict__ x8, const int8_t* __restrict__ gw8,
                   const int8_t* __restrict__ uw8,
                   const float* __restrict__ galpha, const float* __restrict__ gbias,
                   const float* __restrict__ ualpha, const float* __restrict__ ubias,
                   const float* __restrict__ scale_p, int8_t* __restrict__ hq)
{
    __shared__ __align__(16) int8_t lsA[128 * 64];
    __shared__ __align__(16) int8_t lsG[128 * 64];
    __shared__ __align__(16) int8_t lsU[128 * 64];

    const int nwg = gridDim.x;                 // 2752, %8==0
    int bid = blockIdx.x;
    bid = (bid & 7) * (nwg >> 3) + (bid >> 3); // bijective XCD swizzle
    const int mt = bid & 31;                   // 32 M tiles
    const int nt = bid >> 5;                   // 86 N tiles
    const int m0 = mt << 7;
    const int n0 = nt << 7;

    const int tid  = threadIdx.x;
    const int lane = tid & 63;
    const int wid  = tid >> 6;                 // 0..3
    const int wc   = wid;                      // wave column (1M x 4N)
    const int lr   = lane & 15;
    const int rdsw = ((lane >> 4) ^ ((lr >> 1) & 3)) << 4;  // read-side XOR slot

    // staging coords (256 threads cover 64 rows x 64B per call; src pre-swizzled)
    const int srow = tid >> 2;                           // 0..63
    const int scol = ((tid & 3) ^ ((tid >> 3) & 3)) << 4;
    const int woff = wid << 10;

    const int8_t* As = x8  + (size_t)(m0 + srow) * H_DIM + scol;
    const int8_t* Gs = gw8 + (size_t)(n0 + srow) * H_DIM + scol;
    const int8_t* Us = uw8 + (size_t)(n0 + srow) * H_DIM + scol;

    i32x4 accg[8][2], accu[8][2];
#pragma unroll
    for (int mf = 0; mf < 8; ++mf)
#pragma unroll
        for (int nf = 0; nf < 2; ++nf) {
            accg[mf][nf] = i32x4{0, 0, 0, 0};
            accu[mf][nf] = i32x4{0, 0, 0, 0};
        }

    const int aro = lr * 64 + rdsw;                 // + mf*1024, mf=0..7
    const int gro = (wc * 32 + lr) * 64 + rdsw;     // + nf*1024, nf=0..1

    for (int kt = 0; kt < H_DIM / 64; ++kt) {
        const int k0 = kt * 64;
        // ---- stage (6 x global_load_lds x4) ----
        gload_lds16(As + k0,                          &lsA[woff]);
        gload_lds16(As + k0 + (size_t)64 * H_DIM,     &lsA[4096 + woff]);
        gload_lds16(Gs + k0,                          &lsG[woff]);
        gload_lds16(Gs + k0 + (size_t)64 * H_DIM,     &lsG[4096 + woff]);
        gload_lds16(Us + k0,                          &lsU[woff]);
        gload_lds16(Us + k0 + (size_t)64 * H_DIM,     &lsU[4096 + woff]);
        __syncthreads();
        // ---- compute ----
        i32x4 af[8], gf[2], uf[2];
#pragma unroll
        for (int mf = 0; mf < 8; ++mf) af[mf] = *(const i32x4*)&lsA[aro + mf * 1024];
        gf[0] = *(const i32x4*)&lsG[gro];
        gf[1] = *(const i32x4*)&lsG[gro + 1024];
        uf[0] = *(const i32x4*)&lsU[gro];
        uf[1] = *(const i32x4*)&lsU[gro + 1024];
#pragma unroll
        for (int mf = 0; mf < 8; ++mf)
#pragma unroll
            for (int nf = 0; nf < 2; ++nf) {
                accg[mf][nf] = MFMA_I8(af[mf], gf[nf], accg[mf][nf], 0, 0, 0);
                accu[mf][nf] = MFMA_I8(af[mf], uf[nf], accu[mf][nf], 0, 0, 0);
            }
        __syncthreads();
    }

    // ---- epilogue: dequant, SwiGLU, requant ----
    const float scale = *scale_p;
#pragma unroll
    for (int nf = 0; nf < 2; ++nf) {
        const int col = n0 + wc * 32 + nf * 16 + lr;
        const float gA = galpha[col], gB = gbias[col];
        const float uA = ualpha[col], uB = ubias[col];
#pragma unroll
        for (int mf = 0; mf < 8; ++mf) {
            const int row0 = m0 + mf * 16 + (lane >> 4) * 4;
#pragma unroll
            for (int j = 0; j < 4; ++j) {
                float g = (float)accg[mf][nf][j] * gA + gB;
                float u = (float)accu[mf][nf][j] * uA + uB;
                float s = 1.0f / (1.0f + __expf(-g));
                float h = g * s * u;
                float q = rintf(h / scale);
                q = fminf(127.0f, fmaxf(-128.0f, q));
                hq[(size_t)(row0 + j) * I_DIM + col] = (int8_t)q;
            }
        }
    }
}

// ---------------------------------------------------------------------------
// down: BM=256 BN=128 BK=64B, 4 waves (2M x 2N), wave = 128x64 output.
// ---------------------------------------------------------------------------
__global__ __launch_bounds__(256, 2)
void down_kernel(const int8_t* __restrict__ hq, const int8_t* __restrict__ dw8,
                 const float* __restrict__ dalpha, const float* __restrict__ dbias,
                 float* __restrict__ out)
{
    __shared__ __align__(16) int8_t lsA[256 * 64];
    __shared__ __align__(16) int8_t lsB[128 * 64];

    const int nwg = gridDim.x;                 // 512, %8==0
    int bid = blockIdx.x;
    bid = (bid & 7) * (nwg >> 3) + (bid >> 3);
    const int mt = bid & 15;                   // 16 M tiles (256 rows)
    const int nt = bid >> 4;                   // 32 N tiles (128 cols)
    const int m0 = mt << 8;
    const int n0 = nt << 7;

    const int tid  = threadIdx.x;
    const int lane = tid & 63;
    const int wid  = tid >> 6;
    const int wr   = wid >> 1;                 // 0..1
    const int wc   = wid & 1;                  // 0..1
    const int lr   = lane & 15;
    const int rdsw = ((lane >> 4) ^ ((lr >> 1) & 3)) << 4;

    const int srow = tid >> 2;
    const int scol = ((tid & 3) ^ ((tid >> 3) & 3)) << 4;
    const int woff = wid << 10;

    const int8_t* Ap = hq  + (size_t)(m0 + srow) * I_DIM + scol;
    const int8_t* Bp = dw8 + (size_t)(n0 + srow) * I_DIM + scol;

    i32x4 acc[8][4];
#pragma unroll
    for (int mf = 0; mf < 8; ++mf)
#pragma unroll
        for (int nf = 0; nf < 4; ++nf) acc[mf][nf] = i32x4{0, 0, 0, 0};

    const int aro = (wr * 128 + lr) * 64 + rdsw;   // + mf*1024, mf=0..7
    const int bro = (wc * 64 + lr) * 64 + rdsw;    // + nf*1024, nf=0..3

    for (int kt = 0; kt < I_DIM / 64; ++kt) {      // 172 iterations
        const int k0 = kt * 64;
        // ---- stage: A 256 rows (4 calls), B 128 rows (2 calls) ----
        gload_lds16(Ap + k0,                           &lsA[woff]);
        gload_lds16(Ap + k0 + (size_t)64 * I_DIM,      &lsA[4096 + woff]);
        gload_lds16(Ap + k0 + (size_t)128 * I_DIM,     &lsA[8192 + woff]);
        gload_lds16(Ap + k0 + (size_t)192 * I_DIM,     &lsA[12288 + woff]);
        gload_lds16(Bp + k0,                           &lsB[woff]);
        gload_lds16(Bp + k0 + (size_t)64 * I_DIM,      &lsB[4096 + woff]);
        __syncthreads();
        // ---- compute ----
        i32x4 af[8], bf[4];
#pragma unroll
        for (int mf = 0; mf < 8; ++mf) af[mf] = *(const i32x4*)&lsA[aro + mf * 1024];
#pragma unroll
        for (int nf = 0; nf < 4; ++nf) bf[nf] = *(const i32x4*)&lsB[bro + nf * 1024];
#pragma unroll
        for (int mf = 0; mf < 8; ++mf)
#pragma unroll
            for (int nf = 0; nf < 4; ++nf)
                acc[mf][nf] = MFMA_I8(af[mf], bf[nf], acc[mf][nf], 0, 0, 0);
        __syncthreads();
    }

    // ---- epilogue: dequant to fp32 ----
#pragma unroll
    for (int nf = 0; nf < 4; ++nf) {
        const int col = n0 + wc * 64 + nf * 16 + lr;
        const float dA = dalpha[col], dB = dbias[col];
#pragma unroll
        for (int mf = 0; mf < 8; ++mf) {
            const int row0 = m0 + wr * 128 + mf * 16 + (lane >> 4) * 4;
#pragma unroll
            for (int j = 0; j < 4; ++j) {
                out[(size_t)(row0 + j) * H_DIM + col] = (float)acc[mf][nf][j] * dA + dB;
            }
        }
    }
}

extern "C" void kernel_launch(void* const* d_in, const int* in_sizes, int n_in,
                              void* d_out, int out_size, void* d_ws, size_t ws_size,
                              hipStream_t stream) {
    const int* x32  = (const int*)d_in[0];
    const int* gw32 = (const int*)d_in[1];
    const int* uw32 = (const int*)d_in[2];
    const int* dw32 = (const int*)d_in[3];
    const float* ga = (const float*)d_in[4];
    const float* gb = (const float*)d_in[5];
    const float* ua = (const float*)d_in[6];
    const float* ub = (const float*)d_in[7];
    const float* da = (const float*)d_in[8];
    const float* db = (const float*)d_in[9];
    const float* sc = (const float*)d_in[10];
    float* out = (float*)d_out;

    const size_t SZ_X8 = (size_t)T_DIM * H_DIM;
    const size_t SZ_W  = (size_t)I_DIM * H_DIM;
    const size_t SZ_HQ = (size_t)T_DIM * I_DIM;

    int8_t* gw8 = (int8_t*)d_ws;              // reused for dw8 later
    int8_t* uw8 = gw8 + SZ_W;
    int8_t* hq  = uw8 + SZ_W;
    int8_t* x8  = hq + SZ_HQ;

    convert_kernel<<<dim3(2048), dim3(256), 0, stream>>>(x32, x8, (int)(SZ_X8 / 4));
    convert_kernel<<<dim3(2048), dim3(256), 0, stream>>>(gw32, gw8, (int)(SZ_W / 4));
    convert_kernel<<<dim3(2048), dim3(256), 0, stream>>>(uw32, uw8, (int)(SZ_W / 4));
    gateup_kernel<<<dim3(32 * 86), dim3(256), 0, stream>>>(
        x8, gw8, uw8, ga, gb, ua, ub, sc, hq);
    int8_t* dw8 = gw8;   // overwrite gate weights (stream-ordered after gateup)
    convert_kernel<<<dim3(2048), dim3(256), 0, stream>>>(dw32, dw8, (int)(SZ_W / 4));
    down_kernel<<<dim3(16 * 32), dim3(256), 0, stream>>>(hq, dw8, da, db, out);
}

// Round 6
// 732.753 us; speedup vs baseline: 1.3385x; 1.1232x over previous
//
#include <hip/hip_runtime.h>
#include <stdint.h>

#define H_DIM 4096
#define I_DIM 11008
#define T_DIM 4096

typedef int i32x4 __attribute__((ext_vector_type(4)));
typedef const void __attribute__((address_space(1))) gvoid_t;
typedef void __attribute__((address_space(3))) svoid_t;

__device__ __forceinline__ void gload_lds16(const void* gsrc, void* ldst) {
    __builtin_amdgcn_global_load_lds((gvoid_t*)gsrc, (svoid_t*)ldst, 16, 0, 0);
}
__device__ __forceinline__ void wait_vmcnt6() {
    asm volatile("s_waitcnt vmcnt(6)" ::: "memory");
}
__device__ __forceinline__ void wait_vmcnt0() {
    asm volatile("s_waitcnt vmcnt(0)" ::: "memory");
}
__device__ __forceinline__ void wait_lgkm0() {
    asm volatile("s_waitcnt lgkmcnt(0)" ::: "memory");
    __builtin_amdgcn_sched_barrier(0);
}
__device__ __forceinline__ void barrier_() {
    asm volatile("s_barrier" ::: "memory");
}

__device__ __forceinline__ uint32_t pack4(int4 v) {
    uint32_t r = (uint32_t)(uint8_t)v.x;
    r |= (uint32_t)(uint8_t)v.y << 8;
    r |= (uint32_t)(uint8_t)v.z << 16;
    r |= (uint32_t)(uint8_t)v.w << 24;
    return r;
}

// int32 -> int8 pack (truncate low byte; values already int8-range)
__global__ void convert_kernel(const int* __restrict__ src, int8_t* __restrict__ dst,
                               int n4) {
    int idx = blockIdx.x * blockDim.x + threadIdx.x;
    int stride = gridDim.x * blockDim.x;
    for (int i = idx; i < n4; i += stride) {
        int4 v = ((const int4*)src)[i];
        ((uint32_t*)dst)[i] = pack4(v);
    }
}

#define MFMA_I8 __builtin_amdgcn_mfma_i32_16x16x64_i8

// ---------------------------------------------------------------------------
// gateup: BM=128 BN=128 BK=64B, 4 waves (2Mx2N), wave = 64x64 per output (G,U).
// 2-deep double-buffered pipeline: counted vmcnt(6), raw barriers (no drain),
// stage(t+2) issued right after read-certification barrier. XOR-swizzled LDS.
// ---------------------------------------------------------------------------
__global__ __launch_bounds__(256, 2)
void gateup_kernel(const int8_t* __restrict__ x8, const int8_t* __restrict__ gw8,
                   const int8_t* __restrict__ uw8,
                   const float* __restrict__ galpha, const float* __restrict__ gbias,
                   const float* __restrict__ ualpha, const float* __restrict__ ubias,
                   const float* __restrict__ scale_p, int8_t* __restrict__ hq)
{
    __shared__ __align__(16) int8_t lsA[2][128 * 64];
    __shared__ __align__(16) int8_t lsG[2][128 * 64];
    __shared__ __align__(16) int8_t lsU[2][128 * 64];

    const int bid = blockIdx.x;
    const int mt = bid & 31;                   // 32 M tiles (M-major: weight reuse in L2)
    const int nt = bid >> 5;                   // 86 N tiles
    const int m0 = mt << 7;
    const int n0 = nt << 7;

    const int tid  = threadIdx.x;
    const int lane = tid & 63;
    const int wid  = tid >> 6;                 // 0..3
    const int wr   = wid >> 1;                 // 0..1
    const int wc   = wid & 1;                  // 0..1
    const int lr   = lane & 15;
    const int rdsw = ((lane >> 4) ^ ((lr >> 1) & 3)) << 4;  // read-side XOR slot

    // staging coords (256 threads cover 64 rows x 64B per call; src pre-swizzled)
    const int srow = tid >> 2;                           // 0..63
    const int scol = ((tid & 3) ^ ((tid >> 3) & 3)) << 4;
    const int woff = wid << 10;

    const int8_t* As = x8  + (size_t)(m0 + srow) * H_DIM + scol;
    const int8_t* Gs = gw8 + (size_t)(n0 + srow) * H_DIM + scol;
    const int8_t* Us = uw8 + (size_t)(n0 + srow) * H_DIM + scol;

    i32x4 accg[4][4], accu[4][4];
#pragma unroll
    for (int mf = 0; mf < 4; ++mf)
#pragma unroll
        for (int nf = 0; nf < 4; ++nf) {
            accg[mf][nf] = i32x4{0, 0, 0, 0};
            accu[mf][nf] = i32x4{0, 0, 0, 0};
        }

    const int aro = (wr * 64 + lr) * 64 + rdsw;    // + mf*1024
    const int gro = (wc * 64 + lr) * 64 + rdsw;    // + nf*1024

#define STAGE_GU(b, kb) do { \
        gload_lds16(As + (kb),                        &lsA[b][woff]); \
        gload_lds16(As + (kb) + (size_t)64 * H_DIM,   &lsA[b][4096 + woff]); \
        gload_lds16(Gs + (kb),                        &lsG[b][woff]); \
        gload_lds16(Gs + (kb) + (size_t)64 * H_DIM,   &lsG[b][4096 + woff]); \
        gload_lds16(Us + (kb),                        &lsU[b][woff]); \
        gload_lds16(Us + (kb) + (size_t)64 * H_DIM,   &lsU[b][4096 + woff]); \
    } while (0)

    const int NKT = H_DIM / 64;  // 64
    STAGE_GU(0, 0);
    STAGE_GU(1, 64);             // 12 loads in flight per wave

    for (int t = 0; t < NKT; ++t) {
        const int cur = t & 1;
        wait_vmcnt6();           // tile-t loads (issued 2 iters ago) have landed
        barrier_();
        i32x4 af[4], bg[4], bu[4];
#pragma unroll
        for (int mf = 0; mf < 4; ++mf) af[mf] = *(const i32x4*)&lsA[cur][aro + mf * 1024];
#pragma unroll
        for (int nf = 0; nf < 4; ++nf) {
            bg[nf] = *(const i32x4*)&lsG[cur][gro + nf * 1024];
            bu[nf] = *(const i32x4*)&lsU[cur][gro + nf * 1024];
        }
        wait_lgkm0();
        barrier_();              // all waves done reading buf[cur] -> reusable
        {
            const int t2 = (t + 2 < NKT) ? (t + 2) : (t + 2 - NKT);
            STAGE_GU(cur, t2 * 64);   // back to 12 in flight
        }
#pragma unroll
        for (int mf = 0; mf < 4; ++mf)
#pragma unroll
            for (int nf = 0; nf < 4; ++nf) {
                accg[mf][nf] = MFMA_I8(af[mf], bg[nf], accg[mf][nf], 0, 0, 0);
                accu[mf][nf] = MFMA_I8(af[mf], bu[nf], accu[mf][nf], 0, 0, 0);
            }
    }
#undef STAGE_GU
    wait_vmcnt0();   // drain tail prefetches before endpgm

    // ---- epilogue: dequant, SwiGLU, requant ----
    const float scale = *scale_p;
#pragma unroll
    for (int nf = 0; nf < 4; ++nf) {
        const int col = n0 + wc * 64 + nf * 16 + lr;
        const float gA = galpha[col], gB = gbias[col];
        const float uA = ualpha[col], uB = ubias[col];
#pragma unroll
        for (int mf = 0; mf < 4; ++mf) {
            const int row0 = m0 + wr * 64 + mf * 16 + (lane >> 4) * 4;
#pragma unroll
            for (int j = 0; j < 4; ++j) {
                float g = (float)accg[mf][nf][j] * gA + gB;
                float u = (float)accu[mf][nf][j] * uA + uB;
                float s = 1.0f / (1.0f + __expf(-g));
                float h = g * s * u;
                float q = rintf(h / scale);
                q = fminf(127.0f, fmaxf(-128.0f, q));
                hq[(size_t)(row0 + j) * I_DIM + col] = (int8_t)q;
            }
        }
    }
}

// ---------------------------------------------------------------------------
// down: BM=256 BN=128 BK=64B, 4 waves (2M x 2N), wave = 128x64 output.
// Same 2-deep counted-vmcnt pipeline.
// ---------------------------------------------------------------------------
__global__ __launch_bounds__(256, 2)
void down_kernel(const int8_t* __restrict__ hq, const int8_t* __restrict__ dw8,
                 const float* __restrict__ dalpha, const float* __restrict__ dbias,
                 float* __restrict__ out)
{
    __shared__ __align__(16) int8_t lsA[2][256 * 64];
    __shared__ __align__(16) int8_t lsB[2][128 * 64];

    const int bid = blockIdx.x;
    const int mt = bid & 15;                   // 16 M tiles (256 rows)
    const int nt = bid >> 4;                   // 32 N tiles (128 cols)
    const int m0 = mt << 8;
    const int n0 = nt << 7;

    const int tid  = threadIdx.x;
    const int lane = tid & 63;
    const int wid  = tid >> 6;
    const int wr   = wid >> 1;                 // 0..1
    const int wc   = wid & 1;                  // 0..1
    const int lr   = lane & 15;
    const int rdsw = ((lane >> 4) ^ ((lr >> 1) & 3)) << 4;

    const int srow = tid >> 2;
    const int scol = ((tid & 3) ^ ((tid >> 3) & 3)) << 4;
    const int woff = wid << 10;

    const int8_t* Ap = hq  + (size_t)(m0 + srow) * I_DIM + scol;
    const int8_t* Bp = dw8 + (size_t)(n0 + srow) * I_DIM + scol;

    i32x4 acc[8][4];
#pragma unroll
    for (int mf = 0; mf < 8; ++mf)
#pragma unroll
        for (int nf = 0; nf < 4; ++nf) acc[mf][nf] = i32x4{0, 0, 0, 0};

    const int aro = (wr * 128 + lr) * 64 + rdsw;   // + mf*1024, mf=0..7
    const int bro = (wc * 64 + lr) * 64 + rdsw;    // + nf*1024, nf=0..3

#define STAGE_D(b, kb) do { \
        gload_lds16(Ap + (kb),                         &lsA[b][woff]); \
        gload_lds16(Ap + (kb) + (size_t)64 * I_DIM,    &lsA[b][4096 + woff]); \
        gload_lds16(Ap + (kb) + (size_t)128 * I_DIM,   &lsA[b][8192 + woff]); \
        gload_lds16(Ap + (kb) + (size_t)192 * I_DIM,   &lsA[b][12288 + woff]); \
        gload_lds16(Bp + (kb),                         &lsB[b][woff]); \
        gload_lds16(Bp + (kb) + (size_t)64 * I_DIM,    &lsB[b][4096 + woff]); \
    } while (0)

    const int NKT = I_DIM / 64;  // 172
    STAGE_D(0, 0);
    STAGE_D(1, 64);

    for (int t = 0; t < NKT; ++t) {
        const int cur = t & 1;
        wait_vmcnt6();
        barrier_();
        i32x4 af[8], bf[4];
#pragma unroll
        for (int mf = 0; mf < 8; ++mf) af[mf] = *(const i32x4*)&lsA[cur][aro + mf * 1024];
#pragma unroll
        for (int nf = 0; nf < 4; ++nf) bf[nf] = *(const i32x4*)&lsB[cur][bro + nf * 1024];
        wait_lgkm0();
        barrier_();
        {
            const int t2 = (t + 2 < NKT) ? (t + 2) : (t + 2 - NKT);
            STAGE_D(cur, t2 * 64);
        }
#pragma unroll
        for (int mf = 0; mf < 8; ++mf)
#pragma unroll
            for (int nf = 0; nf < 4; ++nf)
                acc[mf][nf] = MFMA_I8(af[mf], bf[nf], acc[mf][nf], 0, 0, 0);
    }
#undef STAGE_D
    wait_vmcnt0();

    // ---- epilogue: dequant to fp32 ----
#pragma unroll
    for (int nf = 0; nf < 4; ++nf) {
        const int col = n0 + wc * 64 + nf * 16 + lr;
        const float dA = dalpha[col], dB = dbias[col];
#pragma unroll
        for (int mf = 0; mf < 8; ++mf) {
            const int row0 = m0 + wr * 128 + mf * 16 + (lane >> 4) * 4;
#pragma unroll
            for (int j = 0; j < 4; ++j) {
                out[(size_t)(row0 + j) * H_DIM + col] = (float)acc[mf][nf][j] * dA + dB;
            }
        }
    }
}

extern "C" void kernel_launch(void* const* d_in, const int* in_sizes, int n_in,
                              void* d_out, int out_size, void* d_ws, size_t ws_size,
                              hipStream_t stream) {
    const int* x32  = (const int*)d_in[0];
    const int* gw32 = (const int*)d_in[1];
    const int* uw32 = (const int*)d_in[2];
    const int* dw32 = (const int*)d_in[3];
    const float* ga = (const float*)d_in[4];
    const float* gb = (const float*)d_in[5];
    const float* ua = (const float*)d_in[6];
    const float* ub = (const float*)d_in[7];
    const float* da = (const float*)d_in[8];
    const float* db = (const float*)d_in[9];
    const float* sc = (const float*)d_in[10];
    float* out = (float*)d_out;

    const size_t SZ_X8 = (size_t)T_DIM * H_DIM;
    const size_t SZ_W  = (size_t)I_DIM * H_DIM;
    const size_t SZ_HQ = (size_t)T_DIM * I_DIM;

    int8_t* gw8 = (int8_t*)d_ws;              // reused for dw8 later
    int8_t* uw8 = gw8 + SZ_W;
    int8_t* hq  = uw8 + SZ_W;
    int8_t* x8  = hq + SZ_HQ;

    convert_kernel<<<dim3(2048), dim3(256), 0, stream>>>(x32, x8, (int)(SZ_X8 / 4));
    convert_kernel<<<dim3(2048), dim3(256), 0, stream>>>(gw32, gw8, (int)(SZ_W / 4));
    convert_kernel<<<dim3(2048), dim3(256), 0, stream>>>(uw32, uw8, (int)(SZ_W / 4));
    gateup_kernel<<<dim3(32 * 86), dim3(256), 0, stream>>>(
        x8, gw8, uw8, ga, gb, ua, ub, sc, hq);
    int8_t* dw8 = gw8;   // overwrite gate weights (stream-ordered after gateup)
    convert_kernel<<<dim3(2048), dim3(256), 0, stream>>>(dw32, dw8, (int)(SZ_W / 4));
    down_kernel<<<dim3(16 * 32), dim3(256), 0, stream>>>(hq, dw8, da, db, out);
}